// Round 11
// baseline (350.339 us; speedup 1.0000x reference)
//
#include <hip/hip_runtime.h>
#include <cfloat>

#define B_ 32
#define N_ 4096
#define C_ 768
#define T_ 1000
#define K_ 20

#define PXB 256           // pixels per k2 block
#define PHC 32            // floats per c-phase (one MFMA K=32 step)
#define NPH (C_/PHC)      // 24 phases
#define GAP_TH 1e-4f
#define MAXF 16384

typedef float f32x4 __attribute__((ext_vector_type(4)));
typedef int   i32x2 __attribute__((ext_vector_type(2)));
typedef short s16x8 __attribute__((ext_vector_type(8)));   // 8 bf16 (4 VGPR)

__device__ __forceinline__ unsigned short bf_rne(float x) {
    unsigned u = __float_as_uint(x);
    return (unsigned short)((u + 0x7fffu + ((u >> 16) & 1u)) >> 16);
}

// ---------------- K1a: vg_logit in fp64 (+ zero counters) ----------------
__global__ __launch_bounds__(256) void k1_logits(const float* __restrict__ g_feat,
                                                 const float* __restrict__ text,
                                                 double* __restrict__ logits,
                                                 int* __restrict__ cnt,
                                                 int* __restrict__ flagcnt) {
    int b = blockIdx.x;
    int wid = threadIdx.x >> 6, lane = threadIdx.x & 63;
    int t = blockIdx.y * 4 + wid;           // grid.y = 250 -> t in [0,1000)
    if (b == 0 && blockIdx.y == 0) {
        for (int i = threadIdx.x; i < B_ * K_; i += 256) cnt[i] = 0;
        if (threadIdx.x == 0) flagcnt[0] = 0;
    }
    const float* g = g_feat + b * C_;
    const float* e = text + t * C_;
    double s = 0.0;
    #pragma unroll
    for (int j = 0; j < 12; ++j) {
        int c = lane + 64 * j;
        s += (double)g[c] * (double)e[c];
    }
    #pragma unroll
    for (int m = 32; m; m >>= 1) s += __shfl_xor(s, m);
    if (lane == 0) logits[b * T_ + t] = s;
}

// ---------------- K1b: top-20 + gather + A-fragment-ordered bf16 hi/lo pack ----------------
__global__ __launch_bounds__(256) void k1b_topk(const double* __restrict__ logits,
                                                const float* __restrict__ text,
                                                float* __restrict__ agg,
                                                unsigned short* __restrict__ Epk) {
    __shared__ unsigned short hiL[32 * C_];   // 48 KB
    __shared__ unsigned short loL[32 * C_];   // 48 KB
    __shared__ int ssel[K_];
    int b = blockIdx.x, tid = threadIdx.x, lane = tid & 63;
    if (tid < 64) {
        double v[16];
        #pragma unroll
        for (int j = 0; j < 16; ++j) {
            int t = lane + 64 * j;
            v[j] = (t < T_) ? logits[b * T_ + t] : -DBL_MAX;
        }
        for (int it = 0; it < K_; ++it) {
            double bv = -DBL_MAX; int bi = 0x7fffffff;
            #pragma unroll
            for (int j = 0; j < 16; ++j) {
                int t = lane + 64 * j;
                if (v[j] > bv) { bv = v[j]; bi = t; }
            }
            #pragma unroll
            for (int m = 32; m; m >>= 1) {
                double ov = __shfl_xor(bv, m); int oi = __shfl_xor(bi, m);
                if (ov > bv || (ov == bv && oi < bi)) { bv = ov; bi = oi; }
            }
            if (lane == 0) ssel[it] = bi;
            #pragma unroll
            for (int j = 0; j < 16; ++j) {
                int t = lane + 64 * j;
                if (t == bi) v[j] = -DBL_MAX;
            }
        }
    }
    __syncthreads();
    for (int i = tid; i < 32 * C_; i += 256) {
        int r = i / C_, c = i - r * C_;
        float v = (r < K_) ? text[ssel[r] * C_ + c] : 0.f;
        if (r < K_) agg[b * K_ * C_ + i] = v;
        unsigned u = __float_as_uint(v);
        float fh = __uint_as_float(u & 0xffff0000u);
        hiL[i] = (unsigned short)(u >> 16);
        loL[i] = bf_rne(v - fh);
    }
    __syncthreads();
    for (int i = tid; i < 24 * 256; i += 256) {
        int p = i >> 8, r = i & 255, f = r >> 6, ln = r & 63;
        int row = (f & 1) * 16 + (ln & 15);
        int col = p * 32 + (ln >> 4) * 8;
        const unsigned short* src = ((f < 2) ? hiL : loL) + row * C_ + col;
        *(s16x8*)(Epk + ((size_t)b * 6144 + i) * 8) = *(const s16x8*)src;
    }
}

// ---------------- K2: per-pixel argmax via bf16-split MFMA, coalesced staging ----------------
__global__ __launch_bounds__(256, 2) void k2_argmax(const float* __restrict__ feat,
                                                    const unsigned short* __restrict__ Epk,
                                                    int* __restrict__ kidx,
                                                    int* __restrict__ cnt,
                                                    int* __restrict__ flagcnt,
                                                    int* __restrict__ flaglist) {
    __shared__ unsigned short hiT[2][PXB * PHC];   // 2 x 16 KB
    __shared__ unsigned short loT[2][PXB * PHC];   // 2 x 16 KB
    __shared__ int scnt[K_];
    int bx = blockIdx.x;
    int b = bx >> 4, tile = bx & 15;
    int n0 = tile * PXB;
    int tid = threadIdx.x, wid = tid >> 6, lane = tid & 63;
    if (tid < K_) scnt[tid] = 0;
    __syncthreads();

    const float* fb = feat + ((size_t)b * N_ + n0) * C_;
    const unsigned short* Eb = Epk + (size_t)b * 6144 * 8;
    int l3 = lane >> 3;                      // sub-row 0..7
    int ch = lane & 7;                       // chunk 0..7 (16B of f row)
    int arow = lane & 15, acg = lane >> 4;   // A/C frag coords

    f32x4 fr[8];
    auto LOADF = [&](int p) {
        #pragma unroll
        for (int i = 0; i < 8; ++i) {
            int row = wid * 64 + i * 8 + l3;
            fr[i] = *(const f32x4*)(fb + (size_t)row * C_ + p * PHC + ch * 4);
        }
    };
    auto CVTW = [&](int buf) {
        int g = ch >> 1, h = ch & 1;
        #pragma unroll
        for (int i = 0; i < 8; ++i) {
            int row = wid * 64 + i * 8 + l3;
            unsigned u0 = __float_as_uint(fr[i].x), u1 = __float_as_uint(fr[i].y);
            unsigned u2 = __float_as_uint(fr[i].z), u3 = __float_as_uint(fr[i].w);
            unsigned ha = (u0 >> 16) | (u1 & 0xffff0000u);
            unsigned hb = (u2 >> 16) | (u3 & 0xffff0000u);
            unsigned la = (unsigned)bf_rne(fr[i].x - __uint_as_float(u0 & 0xffff0000u)) |
                          ((unsigned)bf_rne(fr[i].y - __uint_as_float(u1 & 0xffff0000u)) << 16);
            unsigned lb = (unsigned)bf_rne(fr[i].z - __uint_as_float(u2 & 0xffff0000u)) |
                          ((unsigned)bf_rne(fr[i].w - __uint_as_float(u3 & 0xffff0000u)) << 16);
            int a16 = row * PHC + ((g ^ (row & 3)) * 8) + h * 4;   // shorts
            i32x2 hv = { (int)ha, (int)hb };
            i32x2 lv = { (int)la, (int)lb };
            *(i32x2*)&hiT[buf][a16] = hv;
            *(i32x2*)&loT[buf][a16] = lv;
        }
    };

    s16x8 Ach0, Ach1, Acl0, Acl1, Anh0, Anh1, Anl0, Anl1;
    auto LOADA = [&](int p, s16x8& h0, s16x8& h1, s16x8& l0, s16x8& l1) {
        const s16x8* ap = (const s16x8*)(Eb + (size_t)p * 256 * 8);
        h0 = ap[0 * 64 + lane];
        h1 = ap[1 * 64 + lane];
        l0 = ap[2 * 64 + lane];
        l1 = ap[3 * 64 + lane];
    };

    f32x4 acc0[4], acc1[4];
    #pragma unroll
    for (int i = 0; i < 4; ++i) { acc0[i] = (f32x4)0.f; acc1[i] = (f32x4)0.f; }

    // prologue
    LOADF(0);
    CVTW(0);
    LOADF(1);
    LOADA(0, Ach0, Ach1, Acl0, Acl1);
    LOADA(1, Anh0, Anh1, Anl0, Anl1);

    #pragma unroll 1
    for (int p = 0; p < NPH; ++p) {
        int cur = p & 1;
        if (p + 1 < NPH) {
            CVTW(cur ^ 1);                    // F(p+1) -> other buffer (consumes fr)
            if (p + 2 < NPH) LOADF(p + 2);    // refill fr; lands during next phase
        }
        asm volatile("s_waitcnt lgkmcnt(0)" ::: "memory");   // wave-local ds_write drain
        __builtin_amdgcn_sched_barrier(0);                    // rule #18: no MFMA hoist

        #pragma unroll
        for (int i = 0; i < 4; ++i) {
            int px = wid * 64 + i * 16 + arow;
            int a16 = px * PHC + (acg ^ (px & 3)) * 8;
            s16x8 Bh = *(const s16x8*)&hiT[cur][a16];
            s16x8 Bl = *(const s16x8*)&loT[cur][a16];
            acc0[i] = __builtin_amdgcn_mfma_f32_16x16x32_bf16(Ach0, Bh, acc0[i], 0, 0, 0);
            acc1[i] = __builtin_amdgcn_mfma_f32_16x16x32_bf16(Ach1, Bh, acc1[i], 0, 0, 0);
            acc0[i] = __builtin_amdgcn_mfma_f32_16x16x32_bf16(Ach0, Bl, acc0[i], 0, 0, 0);
            acc1[i] = __builtin_amdgcn_mfma_f32_16x16x32_bf16(Ach1, Bl, acc1[i], 0, 0, 0);
            acc0[i] = __builtin_amdgcn_mfma_f32_16x16x32_bf16(Acl0, Bh, acc0[i], 0, 0, 0);
            acc1[i] = __builtin_amdgcn_mfma_f32_16x16x32_bf16(Acl1, Bh, acc1[i], 0, 0, 0);
        }

        Ach0 = Anh0; Ach1 = Anh1; Acl0 = Anl0; Acl1 = Anl1;
        if (p + 2 < NPH) LOADA(p + 2, Anh0, Anh1, Anl0, Anl1);
    }

    // epilogue: per px-tile top-2 over k (C/D: col=lane&15=px, row=(lane>>4)*4+reg)
    #pragma unroll
    for (int i = 0; i < 4; ++i) {
        int kb = acg * 4;
        float m1 = acc0[i][0]; int i1 = kb; float m2 = -FLT_MAX;
        #pragma unroll
        for (int r = 1; r < 4; ++r) {
            float v = acc0[i][r];
            if (v > m1) { m2 = m1; m1 = v; i1 = kb + r; }
            else if (v > m2) m2 = v;
        }
        if (acg == 0) {                      // k-tile 1: only k=16..19 valid
            #pragma unroll
            for (int r = 0; r < 4; ++r) {
                float v = acc1[i][r];
                if (v > m1) { m2 = m1; m1 = v; i1 = 16 + r; }
                else if (v > m2) m2 = v;
            }
        }
        #pragma unroll
        for (int s = 16; s < 64; s <<= 1) {
            float om1 = __shfl_xor(m1, s); int oi1 = __shfl_xor(i1, s);
            float om2 = __shfl_xor(m2, s);
            if (om1 > m1 || (om1 == m1 && oi1 < i1)) { m2 = fmaxf(m1, om2); m1 = om1; i1 = oi1; }
            else { m2 = fmaxf(m2, om1); }
        }
        if (lane < 16) {
            int n = n0 + wid * 64 + i * 16 + lane;
            kidx[b * N_ + n] = i1;
            atomicAdd(&scnt[i1], 1);
            if (m1 - m2 < GAP_TH) {
                int pos = atomicAdd(flagcnt, 1);
                if (pos < MAXF) flaglist[pos] = b * N_ + n;
            }
        }
    }
    __syncthreads();
    if (tid < K_) atomicAdd(&cnt[b * K_ + tid], scnt[tid]);
}

// ---------------- K2.5: fp64 re-decision for knife-edge pixels ----------------
__global__ __launch_bounds__(256) void k25_refine(const float* __restrict__ feat,
                                                  const float* __restrict__ agg,
                                                  int* __restrict__ kidx,
                                                  int* __restrict__ cnt,
                                                  const int* __restrict__ flagcnt,
                                                  const int* __restrict__ flaglist) {
    int wid = threadIdx.x >> 6, lane = threadIdx.x & 63;
    int wg = blockIdx.x * 4 + wid;
    int nf = flagcnt[0]; if (nf > MAXF) nf = MAXF;
    for (int e = wg; e < nf; e += gridDim.x * 4) {
        int pix = flaglist[e];
        int b = pix >> 12;
        const float* fr = feat + (size_t)pix * C_;
        const float* ebase = agg + b * K_ * C_;
        double fd[12];
        #pragma unroll
        for (int j = 0; j < 12; ++j) fd[j] = (double)fr[lane + 64 * j];
        double best = -DBL_MAX; int bi = 0;
        for (int k = 0; k < K_; ++k) {
            const float* er = ebase + k * C_;
            double s = 0.0;
            #pragma unroll
            for (int j = 0; j < 12; ++j) s += fd[j] * (double)er[lane + 64 * j];
            #pragma unroll
            for (int m = 32; m; m >>= 1) s += __shfl_xor(s, m);
            if (s > best) { best = s; bi = k; }
        }
        if (lane == 0) {
            int old = kidx[pix];
            if (old != bi) {
                kidx[pix] = bi;
                atomicSub(&cnt[b * K_ + old], 1);
                atomicAdd(&cnt[b * K_ + bi], 1);
            }
        }
    }
}

// ---------------- K3s: pre-scale agg rows by 1/(cnt+1) ----------------
__global__ __launch_bounds__(256) void k3s_scale(const float* __restrict__ agg,
                                                 const int* __restrict__ cnt,
                                                 float* __restrict__ sagg) {
    __shared__ float sc[K_];
    int b = blockIdx.x, tid = threadIdx.x;
    if (tid < K_) sc[tid] = 1.0f / ((float)cnt[b * K_ + tid] + 1.0f);  // IEEE div, matches ref
    __syncthreads();
    const f32x4* a4 = (const f32x4*)(agg + (size_t)b * K_ * C_);
    f32x4* s4 = (f32x4*)(sagg + (size_t)b * K_ * C_);
    #pragma unroll 1
    for (int i = tid; i < K_ * (C_ / 4); i += 256) {
        int k = i / (C_ / 4);
        s4[i] = a4[i] * sc[k];
    }
}

// ---------------- K4: gather+store only (8 px/wave, 2-deep pipeline) ----------------
// IDEMPOTENT (no atomics, pure gather+store) -> launched twice this round as a
// timing probe: dur_us delta vs R10 == k4's true duration.
__global__ __launch_bounds__(256) void k4_out(const float* __restrict__ sagg,
                                              const int* __restrict__ kidx,
                                              float* __restrict__ out) {
    int wid = threadIdx.x >> 6, lane = threadIdx.x & 63;
    int wg = blockIdx.x * 4 + wid;          // 16384 waves, 8 px each
    int base = wg * 8;
    int b = base >> 12;                     // wave-uniform (8 | 4096)
    int kk[8];
    #pragma unroll
    for (int i = 0; i < 8; ++i) kk[i] = kidx[base + i];
    const f32x4* sagg4 = (const f32x4*)sagg;
    f32x4* out4 = (f32x4*)out;

    f32x4 va0, va1, va2, vb0, vb1, vb2;
    {
        const f32x4* a4 = sagg4 + (size_t)(b * K_ + kk[0]) * (C_ / 4);
        va0 = a4[lane]; va1 = a4[lane + 64]; va2 = a4[lane + 128];
    }
    #pragma unroll
    for (int i = 0; i < 8; ++i) {
        if (i + 1 < 8) {
            const f32x4* a4 = sagg4 + (size_t)(b * K_ + kk[i + 1]) * (C_ / 4);
            vb0 = a4[lane]; vb1 = a4[lane + 64]; vb2 = a4[lane + 128];
        }
        f32x4* o4 = out4 + (size_t)(base + i) * (C_ / 4);
        o4[lane] = va0; o4[lane + 64] = va1; o4[lane + 128] = va2;
        va0 = vb0; va1 = vb1; va2 = vb2;
    }
}

extern "C" void kernel_launch(void* const* d_in, const int* in_sizes, int n_in,
                              void* d_out, int out_size, void* d_ws, size_t ws_size,
                              hipStream_t stream) {
    const float* g_feat = (const float*)d_in[0];
    const float* feat   = (const float*)d_in[1];
    // d_in[2] = tau: positive scale, numerically irrelevant (attn == y_hard exactly)
    const float* text   = (const float*)d_in[3];
    float* out = (float*)d_out;

    char* ws = (char*)d_ws;
    double* logits        = (double*)(ws + 0);         // 256000 B
    float*  agg           = (float*) (ws + 262144);    // 1966080 B
    int*    cnt           = (int*)   (ws + 2230784);   // 2560 B
    int*    flagc         = (int*)   (ws + 2233344);   // 64 B
    int*    flagl         = (int*)   (ws + 2233408);   // 65536 B
    int*    kidx          = (int*)   (ws + 2301504);   // 524288 B
    unsigned short* Epk   = (unsigned short*)(ws + 2825792);  // 3145728 B
    float*  sagg          = (float*) (ws + 5971520);   // 1966080 B

    k1_logits<<<dim3(32, 250), 256, 0, stream>>>(g_feat, text, logits, cnt, flagc);
    k1b_topk<<<32, 256, 0, stream>>>(logits, text, agg, Epk);
    k2_argmax<<<32 * 16, 256, 0, stream>>>(feat, Epk, kidx, cnt, flagc, flagl);
    k25_refine<<<1024, 256, 0, stream>>>(feat, agg, kidx, cnt, flagc, flagl);
    k3s_scale<<<32, 256, 0, stream>>>(agg, cnt, sagg);
    k4_out<<<4096, 256, 0, stream>>>(sagg, kidx, out);   // probe copy #1
    k4_out<<<4096, 256, 0, stream>>>(sagg, kidx, out);   // real write #2 (identical)
}

// Round 12
// 272.303 us; speedup vs baseline: 1.2866x; 1.2866x over previous
//
#include <hip/hip_runtime.h>
#include <cfloat>

#define B_ 32
#define N_ 4096
#define C_ 768
#define T_ 1000
#define K_ 20

#define PXB 256           // pixels per k2 block
#define PHC 32            // floats per c-phase (one MFMA K=32 step)
#define NPH (C_/PHC)      // 24 phases
#define GAP_TH 1e-4f
#define MAXF 16384

typedef float f32x4 __attribute__((ext_vector_type(4)));
typedef int   i32x2 __attribute__((ext_vector_type(2)));
typedef short s16x8 __attribute__((ext_vector_type(8)));   // 8 bf16 (4 VGPR)

__device__ __forceinline__ unsigned short bf_rne(float x) {
    unsigned u = __float_as_uint(x);
    return (unsigned short)((u + 0x7fffu + ((u >> 16) & 1u)) >> 16);
}

// ---------------- K1a: vg_logit in fp64 (+ zero counters) ----------------
__global__ __launch_bounds__(256) void k1_logits(const float* __restrict__ g_feat,
                                                 const float* __restrict__ text,
                                                 double* __restrict__ logits,
                                                 int* __restrict__ cnt,
                                                 int* __restrict__ flagcnt) {
    int b = blockIdx.x;
    int wid = threadIdx.x >> 6, lane = threadIdx.x & 63;
    int t = blockIdx.y * 4 + wid;           // grid.y = 250 -> t in [0,1000)
    if (b == 0 && blockIdx.y == 0) {
        for (int i = threadIdx.x; i < B_ * K_; i += 256) cnt[i] = 0;
        if (threadIdx.x == 0) flagcnt[0] = 0;
    }
    const float* g = g_feat + b * C_;
    const float* e = text + t * C_;
    double s = 0.0;
    #pragma unroll
    for (int j = 0; j < 12; ++j) {
        int c = lane + 64 * j;
        s += (double)g[c] * (double)e[c];
    }
    #pragma unroll
    for (int m = 32; m; m >>= 1) s += __shfl_xor(s, m);
    if (lane == 0) logits[b * T_ + t] = s;
}

// ---------------- K1b: top-20 + gather + A-fragment-ordered bf16 hi/lo pack ----------------
__global__ __launch_bounds__(256) void k1b_topk(const double* __restrict__ logits,
                                                const float* __restrict__ text,
                                                float* __restrict__ agg,
                                                unsigned short* __restrict__ Epk) {
    __shared__ unsigned short hiL[32 * C_];   // 48 KB
    __shared__ unsigned short loL[32 * C_];   // 48 KB
    __shared__ int ssel[K_];
    int b = blockIdx.x, tid = threadIdx.x, lane = tid & 63;
    if (tid < 64) {
        double v[16];
        #pragma unroll
        for (int j = 0; j < 16; ++j) {
            int t = lane + 64 * j;
            v[j] = (t < T_) ? logits[b * T_ + t] : -DBL_MAX;
        }
        for (int it = 0; it < K_; ++it) {
            double bv = -DBL_MAX; int bi = 0x7fffffff;
            #pragma unroll
            for (int j = 0; j < 16; ++j) {
                int t = lane + 64 * j;
                if (v[j] > bv) { bv = v[j]; bi = t; }
            }
            #pragma unroll
            for (int m = 32; m; m >>= 1) {
                double ov = __shfl_xor(bv, m); int oi = __shfl_xor(bi, m);
                if (ov > bv || (ov == bv && oi < bi)) { bv = ov; bi = oi; }
            }
            if (lane == 0) ssel[it] = bi;
            #pragma unroll
            for (int j = 0; j < 16; ++j) {
                int t = lane + 64 * j;
                if (t == bi) v[j] = -DBL_MAX;
            }
        }
    }
    __syncthreads();
    for (int i = tid; i < 32 * C_; i += 256) {
        int r = i / C_, c = i - r * C_;
        float v = (r < K_) ? text[ssel[r] * C_ + c] : 0.f;
        if (r < K_) agg[b * K_ * C_ + i] = v;
        unsigned u = __float_as_uint(v);
        float fh = __uint_as_float(u & 0xffff0000u);
        hiL[i] = (unsigned short)(u >> 16);
        loL[i] = bf_rne(v - fh);
    }
    __syncthreads();
    for (int i = tid; i < 24 * 256; i += 256) {
        int p = i >> 8, r = i & 255, f = r >> 6, ln = r & 63;
        int row = (f & 1) * 16 + (ln & 15);
        int col = p * 32 + (ln >> 4) * 8;
        const unsigned short* src = ((f < 2) ? hiL : loL) + row * C_ + col;
        *(s16x8*)(Epk + ((size_t)b * 6144 + i) * 8) = *(const s16x8*)src;
    }
}

// ---------------- K2: bf16-split MFMA argmax, 4 blocks/CU, single LDS buffer ----------------
// Wave-private LDS regions -> no block barriers in K-loop; in-wave ordering via
// lgkmcnt(0)+sched_barrier (rule #18). Single 32KB buffer + no A-prefetch regs
// -> LDS 32.2KB, VGPR~110 -> 4 blocks/CU = 4 waves/SIMD: 2x load-issue duty
// cycle (the R11-probe-implied k2 limiter at 2 waves/SIMD).
__global__ __launch_bounds__(256, 4) void k2_argmax(const float* __restrict__ feat,
                                                    const unsigned short* __restrict__ Epk,
                                                    int* __restrict__ kidx,
                                                    int* __restrict__ cnt,
                                                    int* __restrict__ flagcnt,
                                                    int* __restrict__ flaglist) {
    __shared__ unsigned short hiT[PXB * PHC];   // 16 KB
    __shared__ unsigned short loT[PXB * PHC];   // 16 KB
    __shared__ int scnt[K_];
    int bx = blockIdx.x;
    int b = bx >> 4, tile = bx & 15;
    int n0 = tile * PXB;
    int tid = threadIdx.x, wid = tid >> 6, lane = tid & 63;
    if (tid < K_) scnt[tid] = 0;
    __syncthreads();

    const float* fb = feat + ((size_t)b * N_ + n0) * C_;
    const unsigned short* Eb = Epk + (size_t)b * 6144 * 8;
    int l3 = lane >> 3;                      // sub-row 0..7
    int ch = lane & 7;                       // chunk 0..7 (16B of f row)
    int arow = lane & 15, acg = lane >> 4;   // A/C frag coords

    f32x4 fr[8];
    auto LOADF = [&](int p) {
        #pragma unroll
        for (int i = 0; i < 8; ++i) {
            int row = wid * 64 + i * 8 + l3;
            fr[i] = *(const f32x4*)(fb + (size_t)row * C_ + p * PHC + ch * 4);
        }
    };
    auto CVTW = [&]() {
        int g = ch >> 1, h = ch & 1;
        #pragma unroll
        for (int i = 0; i < 8; ++i) {
            int row = wid * 64 + i * 8 + l3;
            unsigned u0 = __float_as_uint(fr[i].x), u1 = __float_as_uint(fr[i].y);
            unsigned u2 = __float_as_uint(fr[i].z), u3 = __float_as_uint(fr[i].w);
            unsigned ha = (u0 >> 16) | (u1 & 0xffff0000u);
            unsigned hb = (u2 >> 16) | (u3 & 0xffff0000u);
            unsigned la = (unsigned)bf_rne(fr[i].x - __uint_as_float(u0 & 0xffff0000u)) |
                          ((unsigned)bf_rne(fr[i].y - __uint_as_float(u1 & 0xffff0000u)) << 16);
            unsigned lb = (unsigned)bf_rne(fr[i].z - __uint_as_float(u2 & 0xffff0000u)) |
                          ((unsigned)bf_rne(fr[i].w - __uint_as_float(u3 & 0xffff0000u)) << 16);
            int a16 = row * PHC + ((g ^ (row & 3)) * 8) + h * 4;   // shorts
            i32x2 hv = { (int)ha, (int)hb };
            i32x2 lv = { (int)la, (int)lb };
            *(i32x2*)&hiT[a16] = hv;
            *(i32x2*)&loT[a16] = lv;
        }
    };

    s16x8 Ach0, Ach1, Acl0, Acl1;
    auto LOADA = [&](int p) {
        const s16x8* ap = (const s16x8*)(Eb + (size_t)p * 256 * 8);
        Ach0 = ap[0 * 64 + lane];
        Ach1 = ap[1 * 64 + lane];
        Acl0 = ap[2 * 64 + lane];
        Acl1 = ap[3 * 64 + lane];
    };

    f32x4 acc0[4], acc1[4];
    #pragma unroll
    for (int i = 0; i < 4; ++i) { acc0[i] = (f32x4)0.f; acc1[i] = (f32x4)0.f; }

    LOADF(0);

    #pragma unroll 1
    for (int p = 0; p < NPH; ++p) {
        LOADA(p);                             // 4 L2-hot loads; CVTW is the slack
        // prior phase's ds_reads drained before overwriting the single buffer:
        asm volatile("s_waitcnt lgkmcnt(0)" ::: "memory");
        __builtin_amdgcn_sched_barrier(0);
        CVTW();                               // consumes fr (vmcnt wait), writes buf
        if (p + 1 < NPH) LOADF(p + 1);        // refill fr; in flight through MFMA
        asm volatile("s_waitcnt lgkmcnt(0)" ::: "memory");   // ds_writes done
        __builtin_amdgcn_sched_barrier(0);                    // rule #18

        #pragma unroll
        for (int i = 0; i < 4; ++i) {
            int px = wid * 64 + i * 16 + arow;
            int a16 = px * PHC + (acg ^ (px & 3)) * 8;
            s16x8 Bh = *(const s16x8*)&hiT[a16];
            s16x8 Bl = *(const s16x8*)&loT[a16];
            acc0[i] = __builtin_amdgcn_mfma_f32_16x16x32_bf16(Ach0, Bh, acc0[i], 0, 0, 0);
            acc1[i] = __builtin_amdgcn_mfma_f32_16x16x32_bf16(Ach1, Bh, acc1[i], 0, 0, 0);
            acc0[i] = __builtin_amdgcn_mfma_f32_16x16x32_bf16(Ach0, Bl, acc0[i], 0, 0, 0);
            acc1[i] = __builtin_amdgcn_mfma_f32_16x16x32_bf16(Ach1, Bl, acc1[i], 0, 0, 0);
            acc0[i] = __builtin_amdgcn_mfma_f32_16x16x32_bf16(Acl0, Bh, acc0[i], 0, 0, 0);
            acc1[i] = __builtin_amdgcn_mfma_f32_16x16x32_bf16(Acl1, Bh, acc1[i], 0, 0, 0);
        }
    }

    // epilogue: per px-tile top-2 over k (C/D: col=lane&15=px, row=(lane>>4)*4+reg)
    #pragma unroll
    for (int i = 0; i < 4; ++i) {
        int kb = acg * 4;
        float m1 = acc0[i][0]; int i1 = kb; float m2 = -FLT_MAX;
        #pragma unroll
        for (int r = 1; r < 4; ++r) {
            float v = acc0[i][r];
            if (v > m1) { m2 = m1; m1 = v; i1 = kb + r; }
            else if (v > m2) m2 = v;
        }
        if (acg == 0) {                      // k-tile 1: only k=16..19 valid
            #pragma unroll
            for (int r = 0; r < 4; ++r) {
                float v = acc1[i][r];
                if (v > m1) { m2 = m1; m1 = v; i1 = 16 + r; }
                else if (v > m2) m2 = v;
            }
        }
        #pragma unroll
        for (int s = 16; s < 64; s <<= 1) {
            float om1 = __shfl_xor(m1, s); int oi1 = __shfl_xor(i1, s);
            float om2 = __shfl_xor(m2, s);
            if (om1 > m1 || (om1 == m1 && oi1 < i1)) { m2 = fmaxf(m1, om2); m1 = om1; i1 = oi1; }
            else { m2 = fmaxf(m2, om1); }
        }
        if (lane < 16) {
            int n = n0 + wid * 64 + i * 16 + lane;
            kidx[b * N_ + n] = i1;
            atomicAdd(&scnt[i1], 1);
            if (m1 - m2 < GAP_TH) {
                int pos = atomicAdd(flagcnt, 1);
                if (pos < MAXF) flaglist[pos] = b * N_ + n;
            }
        }
    }
    __syncthreads();
    if (tid < K_) atomicAdd(&cnt[b * K_ + tid], scnt[tid]);
}

// ---------------- K2.5: fp64 re-decision for knife-edge pixels ----------------
__global__ __launch_bounds__(256) void k25_refine(const float* __restrict__ feat,
                                                  const float* __restrict__ agg,
                                                  int* __restrict__ kidx,
                                                  int* __restrict__ cnt,
                                                  const int* __restrict__ flagcnt,
                                                  const int* __restrict__ flaglist) {
    int wid = threadIdx.x >> 6, lane = threadIdx.x & 63;
    int wg = blockIdx.x * 4 + wid;
    int nf = flagcnt[0]; if (nf > MAXF) nf = MAXF;
    for (int e = wg; e < nf; e += gridDim.x * 4) {
        int pix = flaglist[e];
        int b = pix >> 12;
        const float* fr = feat + (size_t)pix * C_;
        const float* ebase = agg + b * K_ * C_;
        double fd[12];
        #pragma unroll
        for (int j = 0; j < 12; ++j) fd[j] = (double)fr[lane + 64 * j];
        double best = -DBL_MAX; int bi = 0;
        for (int k = 0; k < K_; ++k) {
            const float* er = ebase + k * C_;
            double s = 0.0;
            #pragma unroll
            for (int j = 0; j < 12; ++j) s += fd[j] * (double)er[lane + 64 * j];
            #pragma unroll
            for (int m = 32; m; m >>= 1) s += __shfl_xor(s, m);
            if (s > best) { best = s; bi = k; }
        }
        if (lane == 0) {
            int old = kidx[pix];
            if (old != bi) {
                kidx[pix] = bi;
                atomicSub(&cnt[b * K_ + old], 1);
                atomicAdd(&cnt[b * K_ + bi], 1);
            }
        }
    }
}

// ---------------- K3s: pre-scale agg rows by 1/(cnt+1) ----------------
__global__ __launch_bounds__(256) void k3s_scale(const float* __restrict__ agg,
                                                 const int* __restrict__ cnt,
                                                 float* __restrict__ sagg) {
    __shared__ float sc[K_];
    int b = blockIdx.x, tid = threadIdx.x;
    if (tid < K_) sc[tid] = 1.0f / ((float)cnt[b * K_ + tid] + 1.0f);  // IEEE div, matches ref
    __syncthreads();
    const f32x4* a4 = (const f32x4*)(agg + (size_t)b * K_ * C_);
    f32x4* s4 = (f32x4*)(sagg + (size_t)b * K_ * C_);
    #pragma unroll 1
    for (int i = tid; i < K_ * (C_ / 4); i += 256) {
        int k = i / (C_ / 4);
        s4[i] = a4[i] * sc[k];
    }
}

// ---------------- K4: gather+store only (8 px/wave, 2-deep pipeline) ----------------
__global__ __launch_bounds__(256) void k4_out(const float* __restrict__ sagg,
                                              const int* __restrict__ kidx,
                                              float* __restrict__ out) {
    int wid = threadIdx.x >> 6, lane = threadIdx.x & 63;
    int wg = blockIdx.x * 4 + wid;          // 16384 waves, 8 px each
    int base = wg * 8;
    int b = base >> 12;                     // wave-uniform (8 | 4096)
    int kk[8];
    #pragma unroll
    for (int i = 0; i < 8; ++i) kk[i] = kidx[base + i];
    const f32x4* sagg4 = (const f32x4*)sagg;
    f32x4* out4 = (f32x4*)out;

    f32x4 va0, va1, va2, vb0, vb1, vb2;
    {
        const f32x4* a4 = sagg4 + (size_t)(b * K_ + kk[0]) * (C_ / 4);
        va0 = a4[lane]; va1 = a4[lane + 64]; va2 = a4[lane + 128];
    }
    #pragma unroll
    for (int i = 0; i < 8; ++i) {
        if (i + 1 < 8) {
            const f32x4* a4 = sagg4 + (size_t)(b * K_ + kk[i + 1]) * (C_ / 4);
            vb0 = a4[lane]; vb1 = a4[lane + 64]; vb2 = a4[lane + 128];
        }
        f32x4* o4 = out4 + (size_t)(base + i) * (C_ / 4);
        o4[lane] = va0; o4[lane + 64] = va1; o4[lane + 128] = va2;
        va0 = vb0; va1 = vb1; va2 = vb2;
    }
}

extern "C" void kernel_launch(void* const* d_in, const int* in_sizes, int n_in,
                              void* d_out, int out_size, void* d_ws, size_t ws_size,
                              hipStream_t stream) {
    const float* g_feat = (const float*)d_in[0];
    const float* feat   = (const float*)d_in[1];
    // d_in[2] = tau: positive scale, numerically irrelevant (attn == y_hard exactly)
    const float* text   = (const float*)d_in[3];
    float* out = (float*)d_out;

    char* ws = (char*)d_ws;
    double* logits        = (double*)(ws + 0);         // 256000 B
    float*  agg           = (float*) (ws + 262144);    // 1966080 B
    int*    cnt           = (int*)   (ws + 2230784);   // 2560 B
    int*    flagc         = (int*)   (ws + 2233344);   // 64 B
    int*    flagl         = (int*)   (ws + 2233408);   // 65536 B
    int*    kidx          = (int*)   (ws + 2301504);   // 524288 B
    unsigned short* Epk   = (unsigned short*)(ws + 2825792);  // 3145728 B
    float*  sagg          = (float*) (ws + 5971520);   // 1966080 B

    k1_logits<<<dim3(32, 250), 256, 0, stream>>>(g_feat, text, logits, cnt, flagc);
    k1b_topk<<<32, 256, 0, stream>>>(logits, text, agg, Epk);
    k2_argmax<<<32 * 16, 256, 0, stream>>>(feat, Epk, kidx, cnt, flagc, flagl);
    k25_refine<<<1024, 256, 0, stream>>>(feat, agg, kidx, cnt, flagc, flagl);
    k3s_scale<<<32, 256, 0, stream>>>(agg, cnt, sagg);
    k4_out<<<4096, 256, 0, stream>>>(sagg, kidx, out);
}